// Round 1
// baseline (2153.043 us; speedup 1.0000x reference)
//
#include <hip/hip_runtime.h>
#include <hip/hip_bf16.h>
#include <math.h>

#define B_ROWS 8192
#define DIN    1024
#define DH     1024
#define NHEAD  4
#define HD     256
#define DP     1365
#define DP2    2730
#define LD_UP  2736   // padded ld for up buffer (16B aligned rows)
#define LD_ACT 1376   // padded ld for act buffer (16B aligned rows)

#define TM 128
#define TN 128
#define TK 8

// ---------------------------------------------------------------- LayerNorm
__global__ __launch_bounds__(256) void ln_kernel(const float* __restrict__ x,
                                                 const float* __restrict__ w,
                                                 const float* __restrict__ b,
                                                 float* __restrict__ xn) {
    int row = blockIdx.x;
    int tid = threadIdx.x;
    const float4 v = *(const float4*)(x + (size_t)row * DIN + tid * 4);
    float s  = v.x + v.y + v.z + v.w;
    float sq = v.x*v.x + v.y*v.y + v.z*v.z + v.w*v.w;
    #pragma unroll
    for (int off = 32; off; off >>= 1) {
        s  += __shfl_xor(s, off);
        sq += __shfl_xor(sq, off);
    }
    __shared__ float ss[8];
    int wid = tid >> 6, lane = tid & 63;
    if (lane == 0) { ss[wid] = s; ss[4 + wid] = sq; }
    __syncthreads();
    s  = ss[0] + ss[1] + ss[2] + ss[3];
    sq = ss[4] + ss[5] + ss[6] + ss[7];
    float mu  = s * (1.0f / DIN);
    float var = sq * (1.0f / DIN) - mu * mu;
    float inv = rsqrtf(var + 1e-5f);
    int c = tid * 4;
    float4 wv = *(const float4*)(w + c);
    float4 bv = *(const float4*)(b + c);
    float4 o;
    o.x = (v.x - mu) * inv * wv.x + bv.x;
    o.y = (v.y - mu) * inv * wv.y + bv.y;
    o.z = (v.z - mu) * inv * wv.z + bv.z;
    o.w = (v.w - mu) * inv * wv.w + bv.w;
    *(float4*)(xn + (size_t)row * DIN + c) = o;
}

// ------------------------------------------------- gates GEMM (4 gates via blockIdx.z)
// gate = xn @ W + b + h_prev_head @ R[head] + rb   (K = 1024 + 256)
__global__ __launch_bounds__(256) void gemm_gates(
    const float* __restrict__ xn, const float* __restrict__ h_prev,
    const float* __restrict__ Wz, const float* __restrict__ Wi,
    const float* __restrict__ Wf, const float* __restrict__ Wo,
    const float* __restrict__ bz, const float* __restrict__ bi,
    const float* __restrict__ bf, const float* __restrict__ bo,
    const float* __restrict__ Rz, const float* __restrict__ Ri,
    const float* __restrict__ Rf, const float* __restrict__ Ro,
    const float* __restrict__ rbz, const float* __restrict__ rbi,
    const float* __restrict__ rbf, const float* __restrict__ rbo,
    float* __restrict__ gates) {
    int g = blockIdx.z;
    const float* W    = (g == 0) ? Wz  : (g == 1) ? Wi  : (g == 2) ? Wf  : Wo;
    const float* bias = (g == 0) ? bz  : (g == 1) ? bi  : (g == 2) ? bf  : bo;
    const float* R    = (g == 0) ? Rz  : (g == 1) ? Ri  : (g == 2) ? Rf  : Ro;
    const float* rb   = (g == 0) ? rbz : (g == 1) ? rbi : (g == 2) ? rbf : rbo;

    __shared__ __align__(16) float As[2][TK][TM];
    __shared__ __align__(16) float Bs[2][TK][TN];
    int tid = threadIdx.x;
    int tx = tid & 15, ty = tid >> 4;
    int tx4 = tx * 4, ty4 = ty * 4;
    int m0 = blockIdx.y * TM;
    int n0 = blockIdx.x * TN;
    int head = n0 >> 8;
    int e0 = n0 & 255;
    int arow = tid >> 1, acol = (tid & 1) * 4;
    int brow = tid >> 5, bcol = (tid & 31) * 4;

    const int KW = 1024, NK = (1024 + 256) / TK;

    auto load_g = [&](int kt, float4& av, float4& bv) {
        int k = kt * TK;
        if (k < KW) {
            av = *(const float4*)&xn[(size_t)(m0 + arow) * DIN + k + acol];
            bv = *(const float4*)&W[(size_t)(k + brow) * DH + n0 + bcol];
        } else {
            int k2 = k - KW;
            av = *(const float4*)&h_prev[(size_t)(m0 + arow) * DH + head * HD + k2 + acol];
            bv = *(const float4*)&R[(size_t)(head * HD + k2 + brow) * HD + e0 + bcol];
        }
    };
    auto store_lds = [&](int buf, float4 av, float4 bv) {
        As[buf][acol + 0][arow] = av.x;
        As[buf][acol + 1][arow] = av.y;
        As[buf][acol + 2][arow] = av.z;
        As[buf][acol + 3][arow] = av.w;
        *(float4*)&Bs[buf][brow][bcol] = bv;
    };

    float acc[8][8] = {};
    float4 av, bv;
    load_g(0, av, bv);
    store_lds(0, av, bv);
    __syncthreads();
    int cur = 0;
    for (int kt = 0; kt < NK; ++kt) {
        float4 nav, nbv;
        if (kt + 1 < NK) load_g(kt + 1, nav, nbv);
        #pragma unroll
        for (int kk = 0; kk < TK; ++kk) {
            float4 a0 = *(const float4*)&As[cur][kk][ty4];
            float4 a1 = *(const float4*)&As[cur][kk][ty4 + 64];
            float4 b0 = *(const float4*)&Bs[cur][kk][tx4];
            float4 b1 = *(const float4*)&Bs[cur][kk][tx4 + 64];
            float a[8]  = {a0.x, a0.y, a0.z, a0.w, a1.x, a1.y, a1.z, a1.w};
            float bb[8] = {b0.x, b0.y, b0.z, b0.w, b1.x, b1.y, b1.z, b1.w};
            #pragma unroll
            for (int i = 0; i < 8; ++i)
                #pragma unroll
                for (int j = 0; j < 8; ++j)
                    acc[i][j] = fmaf(a[i], bb[j], acc[i][j]);
        }
        if (kt + 1 < NK) store_lds(cur ^ 1, nav, nbv);
        __syncthreads();
        cur ^= 1;
    }

    float badd[8];
    #pragma unroll
    for (int jb = 0; jb < 2; ++jb)
        #pragma unroll
        for (int j = 0; j < 4; ++j) {
            int c = n0 + tx4 + jb * 64 + j;
            badd[jb * 4 + j] = bias[c] + rb[c];
        }
    float* og = gates + (size_t)g * B_ROWS * DH;
    #pragma unroll
    for (int i = 0; i < 8; ++i) {
        int row = m0 + ((i < 4) ? (ty4 + i) : (64 + ty4 + i - 4));
        #pragma unroll
        for (int jb = 0; jb < 2; ++jb) {
            int c = n0 + tx4 + jb * 64;
            float4 r;
            r.x = acc[i][jb * 4 + 0] + badd[jb * 4 + 0];
            r.y = acc[i][jb * 4 + 1] + badd[jb * 4 + 1];
            r.z = acc[i][jb * 4 + 2] + badd[jb * 4 + 2];
            r.w = acc[i][jb * 4 + 3] + badd[jb * 4 + 3];
            *(float4*)&og[(size_t)row * DH + c] = r;
        }
    }
}

// ------------------------------------- sLSTM pointwise + GroupNorm (per (row,head) wave)
__global__ __launch_bounds__(256) void pointwise_gn(
    const float* __restrict__ gz, const float* __restrict__ gi,
    const float* __restrict__ gf, const float* __restrict__ go,
    const float* __restrict__ c_prev, const float* __restrict__ n_prev,
    const float* __restrict__ m_prev, const float* __restrict__ gn_w,
    const float* __restrict__ gn_b, float* __restrict__ out,
    float* __restrict__ htn) {
    int row = blockIdx.x;
    int tid = threadIdx.x;
    int head = tid >> 6, lane = tid & 63;
    int col = head * HD + lane * 4;
    size_t idx = (size_t)row * DH + col;
    const size_t N = (size_t)B_ROWS * DH;

    float4 z  = *(const float4*)(gz + idx);
    float4 iv = *(const float4*)(gi + idx);
    float4 f  = *(const float4*)(gf + idx);
    float4 o  = *(const float4*)(go + idx);
    float4 cp = *(const float4*)(c_prev + idx);
    float4 np = *(const float4*)(n_prev + idx);
    float4 mp = *(const float4*)(m_prev + idx);

    float zv[4] = {z.x, z.y, z.z, z.w};
    float ivv[4] = {iv.x, iv.y, iv.z, iv.w};
    float fv[4] = {f.x, f.y, f.z, f.w};
    float ov[4] = {o.x, o.y, o.z, o.w};
    float cpv[4] = {cp.x, cp.y, cp.z, cp.w};
    float npv[4] = {np.x, np.y, np.z, np.w};
    float mpv[4] = {mp.x, mp.y, mp.z, mp.w};

    float htv[4], ctv[4], ntv[4], mtv[4];
    float s = 0.f, sq = 0.f;
    #pragma unroll
    for (int j = 0; j < 4; ++j) {
        float zt = tanhf(zv[j]);
        float ot = 1.0f / (1.0f + expf(-ov[j]));
        float mt = fmaxf(fv[j] + mpv[j], ivv[j]);
        float it = expf(ivv[j] - mt);
        float ft = expf(fv[j] + mpv[j] - mt);
        float ct = ft * cpv[j] + it * zt;
        float nt = ft * npv[j] + it;
        float h  = ot * (ct / (nt + 1e-13f));
        htv[j] = h; ctv[j] = ct; ntv[j] = nt; mtv[j] = mt;
        s += h; sq += h * h;
    }
    // outputs: [y, ht, ct, nt, mt]
    *(float4*)(out + N     + idx) = make_float4(htv[0], htv[1], htv[2], htv[3]);
    *(float4*)(out + 2 * N + idx) = make_float4(ctv[0], ctv[1], ctv[2], ctv[3]);
    *(float4*)(out + 3 * N + idx) = make_float4(ntv[0], ntv[1], ntv[2], ntv[3]);
    *(float4*)(out + 4 * N + idx) = make_float4(mtv[0], mtv[1], mtv[2], mtv[3]);

    #pragma unroll
    for (int off = 1; off < 64; off <<= 1) {
        s  += __shfl_xor(s, off);
        sq += __shfl_xor(sq, off);
    }
    float mean = s * (1.0f / HD);
    float var  = fmaxf(sq * (1.0f / HD) - mean * mean, 0.0f);
    float inv  = rsqrtf(var + 1e-5f);
    float4 gw = *(const float4*)(gn_w + col);
    float4 gb = *(const float4*)(gn_b + col);
    float gwv[4] = {gw.x, gw.y, gw.z, gw.w};
    float gbv[4] = {gb.x, gb.y, gb.z, gb.w};
    float4 hn;
    hn.x = (htv[0] - mean) * inv * gwv[0] + gbv[0];
    hn.y = (htv[1] - mean) * inv * gwv[1] + gbv[1];
    hn.z = (htv[2] - mean) * inv * gwv[2] + gbv[2];
    hn.w = (htv[3] - mean) * inv * gwv[3] + gbv[3];
    *(float4*)(htn + idx) = hn;
}

// ---------------------------------------------------------------- up GEMM
__global__ __launch_bounds__(256) void gemm_up(const float* __restrict__ htn,
                                               const float* __restrict__ Wup,
                                               const float* __restrict__ bup,
                                               float* __restrict__ up) {
    __shared__ __align__(16) float As[2][TK][TM];
    __shared__ __align__(16) float Bs[2][TK][TN];
    int tid = threadIdx.x;
    int tx = tid & 15, ty = tid >> 4;
    int tx4 = tx * 4, ty4 = ty * 4;
    int m0 = blockIdx.y * TM;
    int n0 = blockIdx.x * TN;
    int arow = tid >> 1, acol = (tid & 1) * 4;
    int brow = tid >> 5, bcol = (tid & 31) * 4;
    const int NK = 1024 / TK;

    auto load_g = [&](int kt, float4& av, float4& bv) {
        int k = kt * TK;
        av = *(const float4*)&htn[(size_t)(m0 + arow) * DH + k + acol];
        int c0 = n0 + bcol;
        const float* bp = Wup + (size_t)(k + brow) * DP2 + c0;
        float2 u0 = (c0 < DP2)     ? *(const float2*)bp       : make_float2(0.f, 0.f);
        float2 u1 = (c0 + 2 < DP2) ? *(const float2*)(bp + 2) : make_float2(0.f, 0.f);
        bv = make_float4(u0.x, u0.y, u1.x, u1.y);
    };
    auto store_lds = [&](int buf, float4 av, float4 bv) {
        As[buf][acol + 0][arow] = av.x;
        As[buf][acol + 1][arow] = av.y;
        As[buf][acol + 2][arow] = av.z;
        As[buf][acol + 3][arow] = av.w;
        *(float4*)&Bs[buf][brow][bcol] = bv;
    };

    float acc[8][8] = {};
    float4 av, bv;
    load_g(0, av, bv);
    store_lds(0, av, bv);
    __syncthreads();
    int cur = 0;
    for (int kt = 0; kt < NK; ++kt) {
        float4 nav, nbv;
        if (kt + 1 < NK) load_g(kt + 1, nav, nbv);
        #pragma unroll
        for (int kk = 0; kk < TK; ++kk) {
            float4 a0 = *(const float4*)&As[cur][kk][ty4];
            float4 a1 = *(const float4*)&As[cur][kk][ty4 + 64];
            float4 b0 = *(const float4*)&Bs[cur][kk][tx4];
            float4 b1 = *(const float4*)&Bs[cur][kk][tx4 + 64];
            float a[8]  = {a0.x, a0.y, a0.z, a0.w, a1.x, a1.y, a1.z, a1.w};
            float bb[8] = {b0.x, b0.y, b0.z, b0.w, b1.x, b1.y, b1.z, b1.w};
            #pragma unroll
            for (int i = 0; i < 8; ++i)
                #pragma unroll
                for (int j = 0; j < 8; ++j)
                    acc[i][j] = fmaf(a[i], bb[j], acc[i][j]);
        }
        if (kt + 1 < NK) store_lds(cur ^ 1, nav, nbv);
        __syncthreads();
        cur ^= 1;
    }

    #pragma unroll
    for (int i = 0; i < 8; ++i) {
        int row = m0 + ((i < 4) ? (ty4 + i) : (64 + ty4 + i - 4));
        #pragma unroll
        for (int jb = 0; jb < 2; ++jb) {
            int c = n0 + tx4 + jb * 64;
            #pragma unroll
            for (int j = 0; j < 4; ++j) {
                int cc = c + j;
                if (cc < DP2)
                    up[(size_t)row * LD_UP + cc] = acc[i][jb * 4 + j] + bup[cc];
            }
        }
    }
}

// ---------------------------------------------------------------- GEGLU gate
__global__ __launch_bounds__(256) void gelu_gate(const float* __restrict__ up,
                                                 float* __restrict__ act) {
    int row = blockIdx.y;
    int col = blockIdx.x * 256 + threadIdx.x;
    if (col >= LD_ACT) return;
    float v = 0.f;
    if (col < DP) {
        float s = up[(size_t)row * LD_UP + col];
        float g = up[(size_t)row * LD_UP + DP + col];
        v = s * 0.5f * g * (1.0f + erff(g * 0.70710678118654752f));
    }
    act[(size_t)row * LD_ACT + col] = v;  // zero-pads cols [1365,1376)
}

// ---------------------------------------------------------------- down GEMM + residual
__global__ __launch_bounds__(256) void gemm_down(const float* __restrict__ act,
                                                 const float* __restrict__ Wdown,
                                                 const float* __restrict__ bdown,
                                                 const float* __restrict__ x,
                                                 float* __restrict__ y) {
    __shared__ __align__(16) float As[2][TK][TM];
    __shared__ __align__(16) float Bs[2][TK][TN];
    int tid = threadIdx.x;
    int tx = tid & 15, ty = tid >> 4;
    int tx4 = tx * 4, ty4 = ty * 4;
    int m0 = blockIdx.y * TM;
    int n0 = blockIdx.x * TN;
    int arow = tid >> 1, acol = (tid & 1) * 4;
    int brow = tid >> 5, bcol = (tid & 31) * 4;
    const int NK = (DP + TK - 1) / TK;  // 171

    auto load_g = [&](int kt, float4& av, float4& bv) {
        int k = kt * TK;
        av = *(const float4*)&act[(size_t)(m0 + arow) * LD_ACT + k + acol];  // pad is zeroed
        int kb = k + brow;
        bv = (kb < DP) ? *(const float4*)&Wdown[(size_t)kb * DIN + n0 + bcol]
                       : make_float4(0.f, 0.f, 0.f, 0.f);
    };
    auto store_lds = [&](int buf, float4 av, float4 bv) {
        As[buf][acol + 0][arow] = av.x;
        As[buf][acol + 1][arow] = av.y;
        As[buf][acol + 2][arow] = av.z;
        As[buf][acol + 3][arow] = av.w;
        *(float4*)&Bs[buf][brow][bcol] = bv;
    };

    float acc[8][8] = {};
    float4 av, bv;
    load_g(0, av, bv);
    store_lds(0, av, bv);
    __syncthreads();
    int cur = 0;
    for (int kt = 0; kt < NK; ++kt) {
        float4 nav, nbv;
        if (kt + 1 < NK) load_g(kt + 1, nav, nbv);
        #pragma unroll
        for (int kk = 0; kk < TK; ++kk) {
            float4 a0 = *(const float4*)&As[cur][kk][ty4];
            float4 a1 = *(const float4*)&As[cur][kk][ty4 + 64];
            float4 b0 = *(const float4*)&Bs[cur][kk][tx4];
            float4 b1 = *(const float4*)&Bs[cur][kk][tx4 + 64];
            float a[8]  = {a0.x, a0.y, a0.z, a0.w, a1.x, a1.y, a1.z, a1.w};
            float bb[8] = {b0.x, b0.y, b0.z, b0.w, b1.x, b1.y, b1.z, b1.w};
            #pragma unroll
            for (int i = 0; i < 8; ++i)
                #pragma unroll
                for (int j = 0; j < 8; ++j)
                    acc[i][j] = fmaf(a[i], bb[j], acc[i][j]);
        }
        if (kt + 1 < NK) store_lds(cur ^ 1, nav, nbv);
        __syncthreads();
        cur ^= 1;
    }

    #pragma unroll
    for (int i = 0; i < 8; ++i) {
        int row = m0 + ((i < 4) ? (ty4 + i) : (64 + ty4 + i - 4));
        #pragma unroll
        for (int jb = 0; jb < 2; ++jb) {
            int c = n0 + tx4 + jb * 64;
            float4 bd = *(const float4*)(bdown + c);
            float4 xr = *(const float4*)(x + (size_t)row * DIN + c);
            float4 r;
            r.x = acc[i][jb * 4 + 0] + bd.x + xr.x;
            r.y = acc[i][jb * 4 + 1] + bd.y + xr.y;
            r.z = acc[i][jb * 4 + 2] + bd.z + xr.z;
            r.w = acc[i][jb * 4 + 3] + bd.w + xr.w;
            *(float4*)&y[(size_t)row * DIN + c] = r;
        }
    }
}

// ---------------------------------------------------------------- launch
extern "C" void kernel_launch(void* const* d_in, const int* in_sizes, int n_in,
                              void* d_out, int out_size, void* d_ws, size_t ws_size,
                              hipStream_t stream) {
    (void)in_sizes; (void)n_in; (void)out_size; (void)ws_size;
    const float* x      = (const float*)d_in[0];
    const float* h_prev = (const float*)d_in[1];
    const float* c_prev = (const float*)d_in[2];
    const float* n_prev = (const float*)d_in[3];
    const float* m_prev = (const float*)d_in[4];
    const float* ln_w   = (const float*)d_in[5];
    const float* ln_b   = (const float*)d_in[6];
    const float* Wz = (const float*)d_in[7];  const float* bz = (const float*)d_in[8];
    const float* Wi = (const float*)d_in[9];  const float* bi = (const float*)d_in[10];
    const float* Wf = (const float*)d_in[11]; const float* bf = (const float*)d_in[12];
    const float* Wo = (const float*)d_in[13]; const float* bo = (const float*)d_in[14];
    const float* Rz = (const float*)d_in[15]; const float* rbz = (const float*)d_in[16];
    const float* Ri = (const float*)d_in[17]; const float* rbi = (const float*)d_in[18];
    const float* Rf = (const float*)d_in[19]; const float* rbf = (const float*)d_in[20];
    const float* Ro = (const float*)d_in[21]; const float* rbo = (const float*)d_in[22];
    const float* gn_w = (const float*)d_in[23]; const float* gn_b = (const float*)d_in[24];
    const float* Wup  = (const float*)d_in[25]; const float* bup  = (const float*)d_in[26];
    const float* Wdown = (const float*)d_in[27]; const float* bdown = (const float*)d_in[28];

    const size_t NXN = (size_t)B_ROWS * DH;  // 8.39M floats
    float* ws    = (float*)d_ws;
    float* xn    = ws;                 // [0, NXN)           — dead after gemm_gates
    float* gates = ws + NXN;           // [NXN, 5*NXN)       — dead after pointwise_gn
    float* htn   = ws;                 // reuses xn region
    float* up    = ws + NXN;           // reuses gates region, 8192*2736
    float* act   = up + (size_t)B_ROWS * LD_UP;  // 8192*1376

    float* out = (float*)d_out;  // [y, ht, ct, nt, mt], each B_ROWS*DH

    ln_kernel<<<B_ROWS, 256, 0, stream>>>(x, ln_w, ln_b, xn);

    gemm_gates<<<dim3(DH / TN, B_ROWS / TM, 4), 256, 0, stream>>>(
        xn, h_prev, Wz, Wi, Wf, Wo, bz, bi, bf, bo,
        Rz, Ri, Rf, Ro, rbz, rbi, rbf, rbo, gates);

    pointwise_gn<<<B_ROWS, 256, 0, stream>>>(
        gates, gates + NXN, gates + 2 * NXN, gates + 3 * NXN,
        c_prev, n_prev, m_prev, gn_w, gn_b, out, htn);

    gemm_up<<<dim3((DP2 + TN - 1) / TN, B_ROWS / TM), 256, 0, stream>>>(htn, Wup, bup, up);

    gelu_gate<<<dim3((LD_ACT + 255) / 256, B_ROWS), 256, 0, stream>>>(up, act);

    gemm_down<<<dim3(DIN / TN, B_ROWS / TM), 256, 0, stream>>>(act, Wdown, bdown, x, out);
}

// Round 3
// 673.807 us; speedup vs baseline: 3.1953x; 3.1953x over previous
//
#include <hip/hip_runtime.h>
#include <hip/hip_bf16.h>
#include <math.h>

#define B_ROWS 8192
#define DIN    1024
#define DH     1024
#define HD     256
#define DP     1365
#define DP2    2730
#define NUP    2816   // padded N for up GEMM (22 * 128)
#define KDN    1408   // padded K for down GEMM (44 * 32)

typedef __bf16 bf16x8 __attribute__((ext_vector_type(8)));
typedef float  f32x4  __attribute__((ext_vector_type(4)));
typedef unsigned short ushort_t;

__device__ __forceinline__ unsigned short f2bf(float f) {
    union { __hip_bfloat16 b; unsigned short u; } v; v.b = __float2bfloat16(f); return v.u;
}
__device__ __forceinline__ float bf2f(unsigned short u) {
    union { __hip_bfloat16 b; unsigned short u; } v; v.u = u; return __bfloat162float(v.b);
}

// ---------------------------------------------------------------- prep: h_prev -> bf16
__global__ __launch_bounds__(256) void prep_hprev(const float* __restrict__ hp,
                                                  ushort_t* __restrict__ out) {
    size_t i = ((size_t)blockIdx.x * 256 + threadIdx.x) * 8;
    float4 a = *(const float4*)(hp + i);
    float4 b = *(const float4*)(hp + i + 4);
    union { unsigned short s[8]; uint4 v; } o;
    o.s[0] = f2bf(a.x); o.s[1] = f2bf(a.y); o.s[2] = f2bf(a.z); o.s[3] = f2bf(a.w);
    o.s[4] = f2bf(b.x); o.s[5] = f2bf(b.y); o.s[6] = f2bf(b.z); o.s[7] = f2bf(b.w);
    *(uint4*)(out + i) = o.v;
}

// ------------------------------- prep: gate weights -> WT[g][n][k] bf16, K=1280 (W | R-block)
__global__ __launch_bounds__(256) void prep_wgates(
    const float* __restrict__ Wz, const float* __restrict__ Wi,
    const float* __restrict__ Wf, const float* __restrict__ Wo,
    const float* __restrict__ Rz, const float* __restrict__ Ri,
    const float* __restrict__ Rf, const float* __restrict__ Ro,
    ushort_t* __restrict__ WT) {
    int g = blockIdx.z;
    const float* W = (g == 0) ? Wz : (g == 1) ? Wi : (g == 2) ? Wf : Wo;
    const float* R = (g == 0) ? Rz : (g == 1) ? Ri : (g == 2) ? Rf : Ro;
    int n  = blockIdx.x * 256 + threadIdx.x;
    int k0 = blockIdx.y * 8;
    union { unsigned short s[8]; uint4 v; } o;
    if (k0 < 1024) {
        #pragma unroll
        for (int j = 0; j < 8; ++j) o.s[j] = f2bf(W[(size_t)(k0 + j) * DH + n]);
    } else {
        int h = n >> 8, e = n & 255, d0 = k0 - 1024;
        #pragma unroll
        for (int j = 0; j < 8; ++j) o.s[j] = f2bf(R[h * 65536 + (d0 + j) * 256 + e]);
    }
    *(uint4*)(WT + (size_t)g * 1024 * 1280 + (size_t)n * 1280 + k0) = o.v;
}

// ------------------------------- prep: Wup -> WupT[n][k] bf16 (n padded to 2816, pad rows = 0)
__global__ __launch_bounds__(256) void prep_wup(const float* __restrict__ Wup,
                                                ushort_t* __restrict__ WupT) {
    int n  = blockIdx.x * 256 + threadIdx.x;   // < 2816
    int k0 = blockIdx.y * 8;
    union { unsigned short s[8]; uint4 v; } o;
    #pragma unroll
    for (int j = 0; j < 8; ++j)
        o.s[j] = (n < DP2) ? f2bf(Wup[(size_t)(k0 + j) * DP2 + n]) : (unsigned short)0;
    *(uint4*)(WupT + (size_t)n * 1024 + k0) = o.v;
}

// ------------------------------- prep: Wdown -> WdnT[n][k] bf16 (k padded to 1408, pad = 0)
__global__ __launch_bounds__(256) void prep_wdown(const float* __restrict__ Wdown,
                                                  ushort_t* __restrict__ WdnT) {
    int n  = blockIdx.x * 256 + threadIdx.x;   // < 1024
    int k0 = blockIdx.y * 8;
    union { unsigned short s[8]; uint4 v; } o;
    #pragma unroll
    for (int j = 0; j < 8; ++j) {
        int k = k0 + j;
        o.s[j] = (k < DP) ? f2bf(Wdown[(size_t)k * DIN + n]) : (unsigned short)0;
    }
    *(uint4*)(WdnT + (size_t)n * KDN + k0) = o.v;
}

// ---------------------------------------------------------------- LayerNorm -> bf16
__global__ __launch_bounds__(256) void ln_kernel(const float* __restrict__ x,
                                                 const float* __restrict__ w,
                                                 const float* __restrict__ b,
                                                 ushort_t* __restrict__ xn) {
    int row = blockIdx.x;
    int tid = threadIdx.x;
    const float4 v = *(const float4*)(x + (size_t)row * DIN + tid * 4);
    float s  = v.x + v.y + v.z + v.w;
    float sq = v.x*v.x + v.y*v.y + v.z*v.z + v.w*v.w;
    #pragma unroll
    for (int off = 32; off; off >>= 1) {
        s  += __shfl_xor(s, off);
        sq += __shfl_xor(sq, off);
    }
    __shared__ float ss[8];
    int wid = tid >> 6, lane = tid & 63;
    if (lane == 0) { ss[wid] = s; ss[4 + wid] = sq; }
    __syncthreads();
    s  = ss[0] + ss[1] + ss[2] + ss[3];
    sq = ss[4] + ss[5] + ss[6] + ss[7];
    float mu  = s * (1.0f / DIN);
    float var = sq * (1.0f / DIN) - mu * mu;
    float inv = rsqrtf(var + 1e-5f);
    int c = tid * 4;
    float4 wv = *(const float4*)(w + c);
    float4 bv = *(const float4*)(b + c);
    union { unsigned short s4[4]; uint2 v2; } o;
    o.s4[0] = f2bf((v.x - mu) * inv * wv.x + bv.x);
    o.s4[1] = f2bf((v.y - mu) * inv * wv.y + bv.y);
    o.s4[2] = f2bf((v.z - mu) * inv * wv.z + bv.z);
    o.s4[3] = f2bf((v.w - mu) * inv * wv.w + bv.w);
    *(uint2*)(xn + (size_t)row * DIN + c) = o.v2;
}

// ---------------------------------------------------------------- gates GEMM (bf16 MFMA, reg-staged)
// gate[g] = xn @ W[g] + b + h_prev_head @ R[g,head] + rb ; K = 1024 (xn) + 256 (h_prev)
__global__ __launch_bounds__(256) void gemm_gates_bf(
    const ushort_t* __restrict__ xn, const ushort_t* __restrict__ hp,
    const ushort_t* __restrict__ WT,
    const float* __restrict__ bz, const float* __restrict__ bi,
    const float* __restrict__ bf_, const float* __restrict__ bo,
    const float* __restrict__ rbz, const float* __restrict__ rbi,
    const float* __restrict__ rbf, const float* __restrict__ rbo,
    ushort_t* __restrict__ gates) {
    int g = blockIdx.z;
    const float* bias = (g == 0) ? bz  : (g == 1) ? bi  : (g == 2) ? bf_ : bo;
    const float* rb   = (g == 0) ? rbz : (g == 1) ? rbi : (g == 2) ? rbf : rbo;
    const ushort_t* Wg = WT + (size_t)g * 1024 * 1280;

    __shared__ __align__(16) ushort_t As[128 * 32];  // [row][k], 64B rows
    __shared__ __align__(16) ushort_t Bs[128 * 32];
    int tid = threadIdx.x, lane = tid & 63, wave = tid >> 6;
    int wm = wave >> 1, wn = wave & 1;
    int m0 = blockIdx.y * 128, n0 = blockIdx.x * 128;
    int head = n0 >> 8;
    int trow = tid >> 2;          // 0..63
    int tk   = (tid & 3) * 8;     // k element offset (0,8,16,24)
    int l15 = lane & 15, l4 = lane >> 4;

    f32x4 acc[4][4];
    #pragma unroll
    for (int i = 0; i < 4; ++i)
        #pragma unroll
        for (int j = 0; j < 4; ++j) acc[i][j] = (f32x4){0.f, 0.f, 0.f, 0.f};

    for (int kt = 0; kt < 40; ++kt) {
        int k0 = kt * 32;
        const ushort_t* ap = (k0 < 1024) ? xn + k0
                                         : hp + head * 256 + (k0 - 1024);
        bf16x8 a0 = *(const bf16x8*)(ap + (size_t)(m0 + trow) * 1024 + tk);
        bf16x8 a1 = *(const bf16x8*)(ap + (size_t)(m0 + trow + 64) * 1024 + tk);
        bf16x8 b0 = *(const bf16x8*)(Wg + (size_t)(n0 + trow) * 1280 + k0 + tk);
        bf16x8 b1 = *(const bf16x8*)(Wg + (size_t)(n0 + trow + 64) * 1280 + k0 + tk);
        __syncthreads();   // all waves done reading previous tile
        *(bf16x8*)(As + trow * 32 + tk)        = a0;
        *(bf16x8*)(As + (trow + 64) * 32 + tk) = a1;
        *(bf16x8*)(Bs + trow * 32 + tk)        = b0;
        *(bf16x8*)(Bs + (trow + 64) * 32 + tk) = b1;
        __syncthreads();   // writes visible (lgkmcnt-tracked)
        bf16x8 af[4], bv[4];
        #pragma unroll
        for (int i = 0; i < 4; ++i) {
            af[i] = *(const bf16x8*)(As + (wm * 64 + i * 16 + l15) * 32 + l4 * 8);
            bv[i] = *(const bf16x8*)(Bs + (wn * 64 + i * 16 + l15) * 32 + l4 * 8);
        }
        #pragma unroll
        for (int mi = 0; mi < 4; ++mi)
            #pragma unroll
            for (int ni = 0; ni < 4; ++ni)
                acc[mi][ni] = __builtin_amdgcn_mfma_f32_16x16x32_bf16(af[mi], bv[ni], acc[mi][ni], 0, 0, 0);
    }

    ushort_t* og = gates + (size_t)g * B_ROWS * DH;
    #pragma unroll
    for (int ni = 0; ni < 4; ++ni) {
        int col = n0 + wn * 64 + ni * 16 + l15;
        float badd = bias[col] + rb[col];
        #pragma unroll
        for (int mi = 0; mi < 4; ++mi) {
            int rbase = m0 + wm * 64 + mi * 16 + l4 * 4;
            #pragma unroll
            for (int j = 0; j < 4; ++j)
                og[(size_t)(rbase + j) * DH + col] = f2bf(acc[mi][ni][j] + badd);
        }
    }
}

// ---------------------------------------------------------------- pointwise sLSTM + GroupNorm
__global__ __launch_bounds__(256) void pointwise_gn(
    const ushort_t* __restrict__ gbf,
    const float* __restrict__ c_prev, const float* __restrict__ n_prev,
    const float* __restrict__ m_prev, const float* __restrict__ gn_w,
    const float* __restrict__ gn_b, float* __restrict__ out,
    ushort_t* __restrict__ htn) {
    int row = blockIdx.x;
    int tid = threadIdx.x;
    int head = tid >> 6, lane = tid & 63;
    int col = head * HD + lane * 4;
    size_t idx = (size_t)row * DH + col;
    const size_t N = (size_t)B_ROWS * DH;

    float zv[4], ivv[4], fv[4], ov[4];
    {
        union { uint2 v; unsigned short s[4]; } t;
        t.v = *(const uint2*)(gbf + idx);
        for (int j = 0; j < 4; ++j) zv[j] = bf2f(t.s[j]);
        t.v = *(const uint2*)(gbf + N + idx);
        for (int j = 0; j < 4; ++j) ivv[j] = bf2f(t.s[j]);
        t.v = *(const uint2*)(gbf + 2 * N + idx);
        for (int j = 0; j < 4; ++j) fv[j] = bf2f(t.s[j]);
        t.v = *(const uint2*)(gbf + 3 * N + idx);
        for (int j = 0; j < 4; ++j) ov[j] = bf2f(t.s[j]);
    }
    float4 cp = *(const float4*)(c_prev + idx);
    float4 np = *(const float4*)(n_prev + idx);
    float4 mp = *(const float4*)(m_prev + idx);
    float cpv[4] = {cp.x, cp.y, cp.z, cp.w};
    float npv[4] = {np.x, np.y, np.z, np.w};
    float mpv[4] = {mp.x, mp.y, mp.z, mp.w};

    float htv[4], ctv[4], ntv[4], mtv[4];
    float s = 0.f, sq = 0.f;
    #pragma unroll
    for (int j = 0; j < 4; ++j) {
        float zt = tanhf(zv[j]);
        float ot = 1.0f / (1.0f + expf(-ov[j]));
        float mt = fmaxf(fv[j] + mpv[j], ivv[j]);
        float it = expf(ivv[j] - mt);
        float ft = expf(fv[j] + mpv[j] - mt);
        float ct = ft * cpv[j] + it * zt;
        float nt = ft * npv[j] + it;
        float h  = ot * (ct / (nt + 1e-13f));
        htv[j] = h; ctv[j] = ct; ntv[j] = nt; mtv[j] = mt;
        s += h; sq += h * h;
    }
    *(float4*)(out + N     + idx) = make_float4(htv[0], htv[1], htv[2], htv[3]);
    *(float4*)(out + 2 * N + idx) = make_float4(ctv[0], ctv[1], ctv[2], ctv[3]);
    *(float4*)(out + 3 * N + idx) = make_float4(ntv[0], ntv[1], ntv[2], ntv[3]);
    *(float4*)(out + 4 * N + idx) = make_float4(mtv[0], mtv[1], mtv[2], mtv[3]);

    #pragma unroll
    for (int off = 1; off < 64; off <<= 1) {
        s  += __shfl_xor(s, off);
        sq += __shfl_xor(sq, off);
    }
    float mean = s * (1.0f / HD);
    float var  = fmaxf(sq * (1.0f / HD) - mean * mean, 0.0f);
    float inv  = rsqrtf(var + 1e-5f);
    float4 gw = *(const float4*)(gn_w + col);
    float4 gb = *(const float4*)(gn_b + col);
    float gwv[4] = {gw.x, gw.y, gw.z, gw.w};
    float gbv[4] = {gb.x, gb.y, gb.z, gb.w};
    union { unsigned short s4[4]; uint2 v2; } o;
    #pragma unroll
    for (int j = 0; j < 4; ++j)
        o.s4[j] = f2bf((htv[j] - mean) * inv * gwv[j] + gbv[j]);
    *(uint2*)(htn + idx) = o.v2;
}

// ---------------------------------------------------------------- up GEMM (bf16 MFMA, reg-staged)
__global__ __launch_bounds__(256) void gemm_up_bf(const ushort_t* __restrict__ htn,
                                                  const ushort_t* __restrict__ WupT,
                                                  const float* __restrict__ bup,
                                                  ushort_t* __restrict__ up) {
    __shared__ __align__(16) ushort_t As[128 * 32];
    __shared__ __align__(16) ushort_t Bs[128 * 32];
    int tid = threadIdx.x, lane = tid & 63, wave = tid >> 6;
    int wm = wave >> 1, wn = wave & 1;
    int m0 = blockIdx.y * 128, n0 = blockIdx.x * 128;
    int trow = tid >> 2;
    int tk   = (tid & 3) * 8;
    int l15 = lane & 15, l4 = lane >> 4;

    f32x4 acc[4][4];
    #pragma unroll
    for (int i = 0; i < 4; ++i)
        #pragma unroll
        for (int j = 0; j < 4; ++j) acc[i][j] = (f32x4){0.f, 0.f, 0.f, 0.f};

    for (int kt = 0; kt < 32; ++kt) {
        int k0 = kt * 32;
        bf16x8 a0 = *(const bf16x8*)(htn  + (size_t)(m0 + trow) * 1024 + k0 + tk);
        bf16x8 a1 = *(const bf16x8*)(htn  + (size_t)(m0 + trow + 64) * 1024 + k0 + tk);
        bf16x8 b0 = *(const bf16x8*)(WupT + (size_t)(n0 + trow) * 1024 + k0 + tk);
        bf16x8 b1 = *(const bf16x8*)(WupT + (size_t)(n0 + trow + 64) * 1024 + k0 + tk);
        __syncthreads();
        *(bf16x8*)(As + trow * 32 + tk)        = a0;
        *(bf16x8*)(As + (trow + 64) * 32 + tk) = a1;
        *(bf16x8*)(Bs + trow * 32 + tk)        = b0;
        *(bf16x8*)(Bs + (trow + 64) * 32 + tk) = b1;
        __syncthreads();
        bf16x8 af[4], bv[4];
        #pragma unroll
        for (int i = 0; i < 4; ++i) {
            af[i] = *(const bf16x8*)(As + (wm * 64 + i * 16 + l15) * 32 + l4 * 8);
            bv[i] = *(const bf16x8*)(Bs + (wn * 64 + i * 16 + l15) * 32 + l4 * 8);
        }
        #pragma unroll
        for (int mi = 0; mi < 4; ++mi)
            #pragma unroll
            for (int ni = 0; ni < 4; ++ni)
                acc[mi][ni] = __builtin_amdgcn_mfma_f32_16x16x32_bf16(af[mi], bv[ni], acc[mi][ni], 0, 0, 0);
    }

    #pragma unroll
    for (int ni = 0; ni < 4; ++ni) {
        int col = n0 + wn * 64 + ni * 16 + l15;
        float badd = (col < DP2) ? bup[col] : 0.f;
        #pragma unroll
        for (int mi = 0; mi < 4; ++mi) {
            int rbase = m0 + wm * 64 + mi * 16 + l4 * 4;
            #pragma unroll
            for (int j = 0; j < 4; ++j)
                up[(size_t)(rbase + j) * NUP + col] = f2bf(acc[mi][ni][j] + badd);
        }
    }
}

// ---------------------------------------------------------------- GEGLU -> act bf16 (K-padded)
__global__ __launch_bounds__(256) void gelu_kernel(const ushort_t* __restrict__ up,
                                                   ushort_t* __restrict__ act) {
    int row = blockIdx.y;
    int c = blockIdx.x * 256 + threadIdx.x;
    if (c >= KDN) return;
    float v = 0.f;
    if (c < DP) {
        float s = bf2f(up[(size_t)row * NUP + c]);
        float g = bf2f(up[(size_t)row * NUP + DP + c]);
        v = s * 0.5f * g * (1.0f + erff(g * 0.70710678118654752f));
    }
    act[(size_t)row * KDN + c] = f2bf(v);
}

// ---------------------------------------------------------------- down GEMM + residual (fp32 out)
__global__ __launch_bounds__(256) void gemm_down_bf(const ushort_t* __restrict__ act,
                                                    const ushort_t* __restrict__ WdnT,
                                                    const float* __restrict__ bdown,
                                                    const float* __restrict__ x,
                                                    float* __restrict__ y) {
    __shared__ __align__(16) ushort_t As[128 * 32];
    __shared__ __align__(16) ushort_t Bs[128 * 32];
    int tid = threadIdx.x, lane = tid & 63, wave = tid >> 6;
    int wm = wave >> 1, wn = wave & 1;
    int m0 = blockIdx.y * 128, n0 = blockIdx.x * 128;
    int trow = tid >> 2;
    int tk   = (tid & 3) * 8;
    int l15 = lane & 15, l4 = lane >> 4;

    f32x4 acc[4][4];
    #pragma unroll
    for (int i = 0; i < 4; ++i)
        #pragma unroll
        for (int j = 0; j < 4; ++j) acc[i][j] = (f32x4){0.f, 0.f, 0.f, 0.f};

    for (int kt = 0; kt < 44; ++kt) {
        int k0 = kt * 32;
        bf16x8 a0 = *(const bf16x8*)(act  + (size_t)(m0 + trow) * KDN + k0 + tk);
        bf16x8 a1 = *(const bf16x8*)(act  + (size_t)(m0 + trow + 64) * KDN + k0 + tk);
        bf16x8 b0 = *(const bf16x8*)(WdnT + (size_t)(n0 + trow) * KDN + k0 + tk);
        bf16x8 b1 = *(const bf16x8*)(WdnT + (size_t)(n0 + trow + 64) * KDN + k0 + tk);
        __syncthreads();
        *(bf16x8*)(As + trow * 32 + tk)        = a0;
        *(bf16x8*)(As + (trow + 64) * 32 + tk) = a1;
        *(bf16x8*)(Bs + trow * 32 + tk)        = b0;
        *(bf16x8*)(Bs + (trow + 64) * 32 + tk) = b1;
        __syncthreads();
        bf16x8 af[4], bv[4];
        #pragma unroll
        for (int i = 0; i < 4; ++i) {
            af[i] = *(const bf16x8*)(As + (wm * 64 + i * 16 + l15) * 32 + l4 * 8);
            bv[i] = *(const bf16x8*)(Bs + (wn * 64 + i * 16 + l15) * 32 + l4 * 8);
        }
        #pragma unroll
        for (int mi = 0; mi < 4; ++mi)
            #pragma unroll
            for (int ni = 0; ni < 4; ++ni)
                acc[mi][ni] = __builtin_amdgcn_mfma_f32_16x16x32_bf16(af[mi], bv[ni], acc[mi][ni], 0, 0, 0);
    }

    #pragma unroll
    for (int ni = 0; ni < 4; ++ni) {
        int col = n0 + wn * 64 + ni * 16 + l15;
        float bd = bdown[col];
        #pragma unroll
        for (int mi = 0; mi < 4; ++mi) {
            int rbase = m0 + wm * 64 + mi * 16 + l4 * 4;
            #pragma unroll
            for (int j = 0; j < 4; ++j) {
                int r = rbase + j;
                y[(size_t)r * DIN + col] = acc[mi][ni][j] + bd + x[(size_t)r * DIN + col];
            }
        }
    }
}

// ---------------------------------------------------------------- launch
extern "C" void kernel_launch(void* const* d_in, const int* in_sizes, int n_in,
                              void* d_out, int out_size, void* d_ws, size_t ws_size,
                              hipStream_t stream) {
    (void)in_sizes; (void)n_in; (void)out_size; (void)ws_size;
    const float* x      = (const float*)d_in[0];
    const float* h_prev = (const float*)d_in[1];
    const float* c_prev = (const float*)d_in[2];
    const float* n_prev = (const float*)d_in[3];
    const float* m_prev = (const float*)d_in[4];
    const float* ln_w   = (const float*)d_in[5];
    const float* ln_b   = (const float*)d_in[6];
    const float* Wz = (const float*)d_in[7];  const float* bz = (const float*)d_in[8];
    const float* Wi = (const float*)d_in[9];  const float* bi = (const float*)d_in[10];
    const float* Wf = (const float*)d_in[11]; const float* bf_ = (const float*)d_in[12];
    const float* Wo = (const float*)d_in[13]; const float* bo = (const float*)d_in[14];
    const float* Rz = (const float*)d_in[15]; const float* rbz = (const float*)d_in[16];
    const float* Ri = (const float*)d_in[17]; const float* rbi = (const float*)d_in[18];
    const float* Rf = (const float*)d_in[19]; const float* rbf = (const float*)d_in[20];
    const float* Ro = (const float*)d_in[21]; const float* rbo = (const float*)d_in[22];
    const float* gn_w = (const float*)d_in[23]; const float* gn_b = (const float*)d_in[24];
    const float* Wup  = (const float*)d_in[25]; const float* bup  = (const float*)d_in[26];
    const float* Wdown = (const float*)d_in[27]; const float* bdown = (const float*)d_in[28];

    // ---- workspace carve (bytes, all 16B-aligned)
    char* w = (char*)d_ws;
    ushort_t* hp_bf  = (ushort_t*)(w);                       // 16,777,216
    ushort_t* WTg    = (ushort_t*)(w + 16777216);            // 10,485,760
    ushort_t* WupT   = (ushort_t*)(w + 27262976);            //  5,767,168
    ushort_t* WdnT   = (ushort_t*)(w + 33030144);            //  2,883,584
    ushort_t* xn_bf  = (ushort_t*)(w + 35913728);            // 16,777,216 (reused as htn)
    ushort_t* htn_bf = xn_bf;
    char*     big    = w + 52690944;
    ushort_t* gates_bf = (ushort_t*)big;                     // 67,108,864 (dead after pointwise)
    ushort_t* up_bf    = (ushort_t*)big;                     // 46,137,344
    ushort_t* act_bf   = (ushort_t*)(big + 46137344);        // 23,068,672
    float* out = (float*)d_out;  // [y, ht, ct, nt, mt]

    prep_hprev <<<4096, 256, 0, stream>>>(h_prev, hp_bf);
    prep_wgates<<<dim3(4, 160, 4), 256, 0, stream>>>(Wz, Wi, Wf, Wo, Rz, Ri, Rf, Ro, WTg);
    prep_wup   <<<dim3(11, 128), 256, 0, stream>>>(Wup, WupT);
    prep_wdown <<<dim3(4, 176), 256, 0, stream>>>(Wdown, WdnT);
    ln_kernel  <<<B_ROWS, 256, 0, stream>>>(x, ln_w, ln_b, xn_bf);

    gemm_gates_bf<<<dim3(8, 64, 4), 256, 0, stream>>>(
        xn_bf, hp_bf, WTg, bz, bi, bf_, bo, rbz, rbi, rbf, rbo, gates_bf);

    pointwise_gn<<<B_ROWS, 256, 0, stream>>>(
        gates_bf, c_prev, n_prev, m_prev, gn_w, gn_b, out, htn_bf);

    gemm_up_bf<<<dim3(22, 64), 256, 0, stream>>>(htn_bf, WupT, bup, up_bf);

    gelu_kernel<<<dim3(6, B_ROWS), 256, 0, stream>>>(up_bf, act_bf);

    gemm_down_bf<<<dim3(8, 64), 256, 0, stream>>>(act_bf, WdnT, bdown, x, out);
}

// Round 4
// 645.310 us; speedup vs baseline: 3.3364x; 1.0442x over previous
//
#include <hip/hip_runtime.h>
#include <hip/hip_bf16.h>
#include <math.h>

#define B_ROWS 8192
#define DIN    1024
#define DH     1024
#define HD     256
#define DP     1365
#define DP2    2730
#define NUP    2816   // padded N for up GEMM (22 * 128)
#define KDN    1408   // padded K for down GEMM (44 * 32)

typedef __bf16 bf16x8 __attribute__((ext_vector_type(8)));
typedef float  f32x4  __attribute__((ext_vector_type(4)));
typedef unsigned short ushort_t;

__device__ __forceinline__ unsigned short f2bf(float f) {
    union { __hip_bfloat16 b; unsigned short u; } v; v.b = __float2bfloat16(f); return v.u;
}
__device__ __forceinline__ float bf2f(unsigned short u) {
    union { __hip_bfloat16 b; unsigned short u; } v; v.u = u; return __bfloat162float(v.b);
}

// ---------------------------------------------------------------- prep: h_prev -> bf16
__global__ __launch_bounds__(256) void prep_hprev(const float* __restrict__ hp,
                                                  ushort_t* __restrict__ out) {
    size_t i = ((size_t)blockIdx.x * 256 + threadIdx.x) * 8;
    float4 a = *(const float4*)(hp + i);
    float4 b = *(const float4*)(hp + i + 4);
    union { unsigned short s[8]; uint4 v; } o;
    o.s[0] = f2bf(a.x); o.s[1] = f2bf(a.y); o.s[2] = f2bf(a.z); o.s[3] = f2bf(a.w);
    o.s[4] = f2bf(b.x); o.s[5] = f2bf(b.y); o.s[6] = f2bf(b.z); o.s[7] = f2bf(b.w);
    *(uint4*)(out + i) = o.v;
}

// ------------------------------- prep: gate weights -> WT[g][n][k] bf16, K=1280 (W | R-block)
__global__ __launch_bounds__(256) void prep_wgates(
    const float* __restrict__ Wz, const float* __restrict__ Wi,
    const float* __restrict__ Wf, const float* __restrict__ Wo,
    const float* __restrict__ Rz, const float* __restrict__ Ri,
    const float* __restrict__ Rf, const float* __restrict__ Ro,
    ushort_t* __restrict__ WT) {
    int g = blockIdx.z;
    const float* W = (g == 0) ? Wz : (g == 1) ? Wi : (g == 2) ? Wf : Wo;
    const float* R = (g == 0) ? Rz : (g == 1) ? Ri : (g == 2) ? Rf : Ro;
    int n  = blockIdx.x * 256 + threadIdx.x;
    int k0 = blockIdx.y * 8;
    union { unsigned short s[8]; uint4 v; } o;
    if (k0 < 1024) {
        #pragma unroll
        for (int j = 0; j < 8; ++j) o.s[j] = f2bf(W[(size_t)(k0 + j) * DH + n]);
    } else {
        int h = n >> 8, e = n & 255, d0 = k0 - 1024;
        #pragma unroll
        for (int j = 0; j < 8; ++j) o.s[j] = f2bf(R[h * 65536 + (d0 + j) * 256 + e]);
    }
    *(uint4*)(WT + (size_t)g * 1024 * 1280 + (size_t)n * 1280 + k0) = o.v;
}

// ------------------------------- prep: Wup -> WupT[n][k] bf16 (n padded to 2816, pad rows = 0)
__global__ __launch_bounds__(256) void prep_wup(const float* __restrict__ Wup,
                                                ushort_t* __restrict__ WupT) {
    int n  = blockIdx.x * 256 + threadIdx.x;   // < 2816
    int k0 = blockIdx.y * 8;
    union { unsigned short s[8]; uint4 v; } o;
    #pragma unroll
    for (int j = 0; j < 8; ++j)
        o.s[j] = (n < DP2) ? f2bf(Wup[(size_t)(k0 + j) * DP2 + n]) : (unsigned short)0;
    *(uint4*)(WupT + (size_t)n * 1024 + k0) = o.v;
}

// ------------------------------- prep: Wdown -> WdnT[n][k] bf16 (k padded to 1408, pad = 0)
__global__ __launch_bounds__(256) void prep_wdown(const float* __restrict__ Wdown,
                                                  ushort_t* __restrict__ WdnT) {
    int n  = blockIdx.x * 256 + threadIdx.x;   // < 1024
    int k0 = blockIdx.y * 8;
    union { unsigned short s[8]; uint4 v; } o;
    #pragma unroll
    for (int j = 0; j < 8; ++j) {
        int k = k0 + j;
        o.s[j] = (k < DP) ? f2bf(Wdown[(size_t)k * DIN + n]) : (unsigned short)0;
    }
    *(uint4*)(WdnT + (size_t)n * KDN + k0) = o.v;
}

// ---------------------------------------------------------------- LayerNorm -> bf16
__global__ __launch_bounds__(256) void ln_kernel(const float* __restrict__ x,
                                                 const float* __restrict__ w,
                                                 const float* __restrict__ b,
                                                 ushort_t* __restrict__ xn) {
    int row = blockIdx.x;
    int tid = threadIdx.x;
    const float4 v = *(const float4*)(x + (size_t)row * DIN + tid * 4);
    float s  = v.x + v.y + v.z + v.w;
    float sq = v.x*v.x + v.y*v.y + v.z*v.z + v.w*v.w;
    #pragma unroll
    for (int off = 32; off; off >>= 1) {
        s  += __shfl_xor(s, off);
        sq += __shfl_xor(sq, off);
    }
    __shared__ float ss[8];
    int wid = tid >> 6, lane = tid & 63;
    if (lane == 0) { ss[wid] = s; ss[4 + wid] = sq; }
    __syncthreads();
    s  = ss[0] + ss[1] + ss[2] + ss[3];
    sq = ss[4] + ss[5] + ss[6] + ss[7];
    float mu  = s * (1.0f / DIN);
    float var = sq * (1.0f / DIN) - mu * mu;
    float inv = rsqrtf(var + 1e-5f);
    int c = tid * 4;
    float4 wv = *(const float4*)(w + c);
    float4 bv = *(const float4*)(b + c);
    union { unsigned short s4[4]; uint2 v2; } o;
    o.s4[0] = f2bf((v.x - mu) * inv * wv.x + bv.x);
    o.s4[1] = f2bf((v.y - mu) * inv * wv.y + bv.y);
    o.s4[2] = f2bf((v.z - mu) * inv * wv.z + bv.z);
    o.s4[3] = f2bf((v.w - mu) * inv * wv.w + bv.w);
    *(uint2*)(xn + (size_t)row * DIN + c) = o.v2;
}

// LDS layout (conflict-free both sides): addr(row,kg) = (row>>4)*1024 + kg*256 + (row&15)*16
// ds_write: wave w lanes cover one contiguous 1KB chunk; ds_read: fragment = contiguous 1KB.

// ---------------------------------------------------------------- gates GEMM (bf16 MFMA)
// gate[g] = xn @ W[g] + b + h_prev_head @ R[g,head] + rb ; K = 1024 (xn) + 256 (h_prev)
__global__ __launch_bounds__(256) void gemm_gates_bf(
    const ushort_t* __restrict__ xn, const ushort_t* __restrict__ hp,
    const ushort_t* __restrict__ WT,
    const float* __restrict__ bz, const float* __restrict__ bi,
    const float* __restrict__ bf_, const float* __restrict__ bo,
    const float* __restrict__ rbz, const float* __restrict__ rbi,
    const float* __restrict__ rbf, const float* __restrict__ rbo,
    ushort_t* __restrict__ gates) {
    // bijective XCD swizzle over 2048 blocks (grid 8 x 64 x 4)
    int bid = blockIdx.x + (blockIdx.y << 3) + (blockIdx.z << 9);
    int wgs = (bid & 7) * 256 + (bid >> 3);
    int bxi = wgs & 7, rest = wgs >> 3, byi = rest & 63;
    int g   = rest >> 6;
    const float* bias = (g == 0) ? bz  : (g == 1) ? bi  : (g == 2) ? bf_ : bo;
    const float* rb   = (g == 0) ? rbz : (g == 1) ? rbi : (g == 2) ? rbf : rbo;
    const ushort_t* Wg = WT + (size_t)g * 1024 * 1280;

    __shared__ __align__(16) char Ash[2][8192];
    __shared__ __align__(16) char Bsh[2][8192];
    int tid = threadIdx.x, lane = tid & 63, wave = tid >> 6;
    int wm = wave >> 1, wn = wave & 1;
    int m0 = byi * 128, n0 = bxi * 128;
    int head = n0 >> 8;
    int trow = tid >> 2, kg = tid & 3, tk = kg * 8;
    int l15 = lane & 15, l4 = lane >> 4;
    int wa  = ((trow >> 4) << 10) + (kg << 8) + ((trow & 15) << 4);
    int raA = (wm << 12) + (l4 << 8) + (l15 << 4);
    int raB = (wn << 12) + (l4 << 8) + (l15 << 4);

    f32x4 acc[4][4];
    #pragma unroll
    for (int i = 0; i < 4; ++i)
        #pragma unroll
        for (int j = 0; j < 4; ++j) acc[i][j] = (f32x4){0.f, 0.f, 0.f, 0.f};

    const ushort_t* aX = xn + (size_t)(m0 + trow) * 1024 + tk;
    const ushort_t* aH = hp + (size_t)(m0 + trow) * 1024 + head * 256 + tk;
    const ushort_t* bW = Wg + (size_t)(n0 + trow) * 1280 + tk;

    auto loadAB = [&](int kt, bf16x8& a0, bf16x8& a1, bf16x8& b0, bf16x8& b1) {
        const ushort_t* p = (kt < 32) ? aX + kt * 32 : aH + (kt - 32) * 32;
        a0 = *(const bf16x8*)p;
        a1 = *(const bf16x8*)(p + 64 * 1024);
        const ushort_t* q = bW + kt * 32;
        b0 = *(const bf16x8*)q;
        b1 = *(const bf16x8*)(q + 64 * 1280);
    };
    auto stage = [&](char* A, char* Bb, bf16x8 a0, bf16x8 a1, bf16x8 b0, bf16x8 b1) {
        *(bf16x8*)(A + wa)         = a0;
        *(bf16x8*)(A + wa + 4096)  = a1;
        *(bf16x8*)(Bb + wa)        = b0;
        *(bf16x8*)(Bb + wa + 4096) = b1;
    };
    auto compute = [&](const char* A, const char* Bb) {
        bf16x8 af[4], bv[4];
        #pragma unroll
        for (int i = 0; i < 4; ++i) {
            af[i] = *(const bf16x8*)(A  + raA + i * 1024);
            bv[i] = *(const bf16x8*)(Bb + raB + i * 1024);
        }
        #pragma unroll
        for (int mi = 0; mi < 4; ++mi)
            #pragma unroll
            for (int ni = 0; ni < 4; ++ni)
                acc[mi][ni] = __builtin_amdgcn_mfma_f32_16x16x32_bf16(af[mi], bv[ni], acc[mi][ni], 0, 0, 0);
    };

    {
        bf16x8 a0, a1, b0, b1;
        loadAB(0, a0, a1, b0, b1);
        stage(Ash[0], Bsh[0], a0, a1, b0, b1);
    }
    __syncthreads();
    for (int kt = 0; kt < 40; kt += 2) {
        bf16x8 a0, a1, b0, b1;
        loadAB(kt + 1, a0, a1, b0, b1);        // issue early; latency hides under MFMA
        compute(Ash[0], Bsh[0]);
        stage(Ash[1], Bsh[1], a0, a1, b0, b1); // vmcnt wait lands here, after compute
        __syncthreads();
        if (kt + 2 < 40) loadAB(kt + 2, a0, a1, b0, b1);
        compute(Ash[1], Bsh[1]);
        if (kt + 2 < 40) {
            stage(Ash[0], Bsh[0], a0, a1, b0, b1);
            __syncthreads();
        }
    }

    ushort_t* og = gates + (size_t)g * B_ROWS * DH;
    #pragma unroll
    for (int ni = 0; ni < 4; ++ni) {
        int col = n0 + wn * 64 + ni * 16 + l15;
        float badd = bias[col] + rb[col];
        #pragma unroll
        for (int mi = 0; mi < 4; ++mi) {
            int rbase = m0 + wm * 64 + mi * 16 + l4 * 4;
            #pragma unroll
            for (int j = 0; j < 4; ++j)
                og[(size_t)(rbase + j) * DH + col] = f2bf(acc[mi][ni][j] + badd);
        }
    }
}

// ---------------------------------------------------------------- pointwise sLSTM + GroupNorm
__global__ __launch_bounds__(256) void pointwise_gn(
    const ushort_t* __restrict__ gbf,
    const float* __restrict__ c_prev, const float* __restrict__ n_prev,
    const float* __restrict__ m_prev, const float* __restrict__ gn_w,
    const float* __restrict__ gn_b, float* __restrict__ out,
    ushort_t* __restrict__ htn) {
    int row = blockIdx.x;
    int tid = threadIdx.x;
    int head = tid >> 6, lane = tid & 63;
    int col = head * HD + lane * 4;
    size_t idx = (size_t)row * DH + col;
    const size_t N = (size_t)B_ROWS * DH;

    float zv[4], ivv[4], fv[4], ov[4];
    {
        union { uint2 v; unsigned short s[4]; } t;
        t.v = *(const uint2*)(gbf + idx);
        for (int j = 0; j < 4; ++j) zv[j] = bf2f(t.s[j]);
        t.v = *(const uint2*)(gbf + N + idx);
        for (int j = 0; j < 4; ++j) ivv[j] = bf2f(t.s[j]);
        t.v = *(const uint2*)(gbf + 2 * N + idx);
        for (int j = 0; j < 4; ++j) fv[j] = bf2f(t.s[j]);
        t.v = *(const uint2*)(gbf + 3 * N + idx);
        for (int j = 0; j < 4; ++j) ov[j] = bf2f(t.s[j]);
    }
    float4 cp = *(const float4*)(c_prev + idx);
    float4 np = *(const float4*)(n_prev + idx);
    float4 mp = *(const float4*)(m_prev + idx);
    float cpv[4] = {cp.x, cp.y, cp.z, cp.w};
    float npv[4] = {np.x, np.y, np.z, np.w};
    float mpv[4] = {mp.x, mp.y, mp.z, mp.w};

    float htv[4], ctv[4], ntv[4], mtv[4];
    float s = 0.f, sq = 0.f;
    #pragma unroll
    for (int j = 0; j < 4; ++j) {
        float zt = tanhf(zv[j]);
        float ot = 1.0f / (1.0f + expf(-ov[j]));
        float mt = fmaxf(fv[j] + mpv[j], ivv[j]);
        float it = expf(ivv[j] - mt);
        float ft = expf(fv[j] + mpv[j] - mt);
        float ct = ft * cpv[j] + it * zt;
        float nt = ft * npv[j] + it;
        float h  = ot * (ct / (nt + 1e-13f));
        htv[j] = h; ctv[j] = ct; ntv[j] = nt; mtv[j] = mt;
        s += h; sq += h * h;
    }
    *(float4*)(out + N     + idx) = make_float4(htv[0], htv[1], htv[2], htv[3]);
    *(float4*)(out + 2 * N + idx) = make_float4(ctv[0], ctv[1], ctv[2], ctv[3]);
    *(float4*)(out + 3 * N + idx) = make_float4(ntv[0], ntv[1], ntv[2], ntv[3]);
    *(float4*)(out + 4 * N + idx) = make_float4(mtv[0], mtv[1], mtv[2], mtv[3]);

    #pragma unroll
    for (int off = 1; off < 64; off <<= 1) {
        s  += __shfl_xor(s, off);
        sq += __shfl_xor(sq, off);
    }
    float mean = s * (1.0f / HD);
    float var  = fmaxf(sq * (1.0f / HD) - mean * mean, 0.0f);
    float inv  = rsqrtf(var + 1e-5f);
    float4 gw = *(const float4*)(gn_w + col);
    float4 gb = *(const float4*)(gn_b + col);
    float gwv[4] = {gw.x, gw.y, gw.z, gw.w};
    float gbv[4] = {gb.x, gb.y, gb.z, gb.w};
    union { unsigned short s4[4]; uint2 v2; } o;
    #pragma unroll
    for (int j = 0; j < 4; ++j)
        o.s4[j] = f2bf((htv[j] - mean) * inv * gwv[j] + gbv[j]);
    *(uint2*)(htn + idx) = o.v2;
}

// ---------------------------------------------------------------- up GEMM (bf16 MFMA)
__global__ __launch_bounds__(256) void gemm_up_bf(const ushort_t* __restrict__ htn,
                                                  const ushort_t* __restrict__ WupT,
                                                  const float* __restrict__ bup,
                                                  ushort_t* __restrict__ up) {
    // bijective XCD swizzle over 1408 blocks (grid 22 x 64)
    int bid = blockIdx.x + blockIdx.y * 22;
    int wgs = (bid & 7) * 176 + (bid >> 3);
    int bxi = wgs % 22, byi = wgs / 22;

    __shared__ __align__(16) char Ash[2][8192];
    __shared__ __align__(16) char Bsh[2][8192];
    int tid = threadIdx.x, lane = tid & 63, wave = tid >> 6;
    int wm = wave >> 1, wn = wave & 1;
    int m0 = byi * 128, n0 = bxi * 128;
    int trow = tid >> 2, kg = tid & 3, tk = kg * 8;
    int l15 = lane & 15, l4 = lane >> 4;
    int wa  = ((trow >> 4) << 10) + (kg << 8) + ((trow & 15) << 4);
    int raA = (wm << 12) + (l4 << 8) + (l15 << 4);
    int raB = (wn << 12) + (l4 << 8) + (l15 << 4);

    f32x4 acc[4][4];
    #pragma unroll
    for (int i = 0; i < 4; ++i)
        #pragma unroll
        for (int j = 0; j < 4; ++j) acc[i][j] = (f32x4){0.f, 0.f, 0.f, 0.f};

    const ushort_t* aP = htn  + (size_t)(m0 + trow) * 1024 + tk;
    const ushort_t* bP = WupT + (size_t)(n0 + trow) * 1024 + tk;

    auto loadAB = [&](int kt, bf16x8& a0, bf16x8& a1, bf16x8& b0, bf16x8& b1) {
        const ushort_t* p = aP + kt * 32;
        a0 = *(const bf16x8*)p;
        a1 = *(const bf16x8*)(p + 64 * 1024);
        const ushort_t* q = bP + kt * 32;
        b0 = *(const bf16x8*)q;
        b1 = *(const bf16x8*)(q + 64 * 1024);
    };
    auto stage = [&](char* A, char* Bb, bf16x8 a0, bf16x8 a1, bf16x8 b0, bf16x8 b1) {
        *(bf16x8*)(A + wa)         = a0;
        *(bf16x8*)(A + wa + 4096)  = a1;
        *(bf16x8*)(Bb + wa)        = b0;
        *(bf16x8*)(Bb + wa + 4096) = b1;
    };
    auto compute = [&](const char* A, const char* Bb) {
        bf16x8 af[4], bv[4];
        #pragma unroll
        for (int i = 0; i < 4; ++i) {
            af[i] = *(const bf16x8*)(A  + raA + i * 1024);
            bv[i] = *(const bf16x8*)(Bb + raB + i * 1024);
        }
        #pragma unroll
        for (int mi = 0; mi < 4; ++mi)
            #pragma unroll
            for (int ni = 0; ni < 4; ++ni)
                acc[mi][ni] = __builtin_amdgcn_mfma_f32_16x16x32_bf16(af[mi], bv[ni], acc[mi][ni], 0, 0, 0);
    };

    {
        bf16x8 a0, a1, b0, b1;
        loadAB(0, a0, a1, b0, b1);
        stage(Ash[0], Bsh[0], a0, a1, b0, b1);
    }
    __syncthreads();
    for (int kt = 0; kt < 32; kt += 2) {
        bf16x8 a0, a1, b0, b1;
        loadAB(kt + 1, a0, a1, b0, b1);
        compute(Ash[0], Bsh[0]);
        stage(Ash[1], Bsh[1], a0, a1, b0, b1);
        __syncthreads();
        if (kt + 2 < 32) loadAB(kt + 2, a0, a1, b0, b1);
        compute(Ash[1], Bsh[1]);
        if (kt + 2 < 32) {
            stage(Ash[0], Bsh[0], a0, a1, b0, b1);
            __syncthreads();
        }
    }

    #pragma unroll
    for (int ni = 0; ni < 4; ++ni) {
        int col = n0 + wn * 64 + ni * 16 + l15;
        float badd = (col < DP2) ? bup[col] : 0.f;
        #pragma unroll
        for (int mi = 0; mi < 4; ++mi) {
            int rbase = m0 + wm * 64 + mi * 16 + l4 * 4;
            #pragma unroll
            for (int j = 0; j < 4; ++j)
                up[(size_t)(rbase + j) * NUP + col] = f2bf(acc[mi][ni][j] + badd);
        }
    }
}

// ---------------------------------------------------------------- GEGLU -> act bf16 (K-padded)
__global__ __launch_bounds__(256) void gelu_kernel(const ushort_t* __restrict__ up,
                                                   ushort_t* __restrict__ act) {
    int row = blockIdx.y;
    int c = blockIdx.x * 256 + threadIdx.x;
    if (c >= KDN) return;
    float v = 0.f;
    if (c < DP) {
        float s = bf2f(up[(size_t)row * NUP + c]);
        float g = bf2f(up[(size_t)row * NUP + DP + c]);
        v = s * 0.5f * g * (1.0f + erff(g * 0.70710678118654752f));
    }
    act[(size_t)row * KDN + c] = f2bf(v);  // zero-pads cols [1365,1408)
}

// ---------------------------------------------------------------- down GEMM + residual (fp32 out)
__global__ __launch_bounds__(256) void gemm_down_bf(const ushort_t* __restrict__ act,
                                                    const ushort_t* __restrict__ WdnT,
                                                    const float* __restrict__ bdown,
                                                    const float* __restrict__ x,
                                                    float* __restrict__ y) {
    // bijective XCD swizzle over 512 blocks (grid 8 x 64)
    int bid = blockIdx.x + (blockIdx.y << 3);
    int wgs = (bid & 7) * 64 + (bid >> 3);
    int bxi = wgs & 7, byi = wgs >> 3;

    __shared__ __align__(16) char Ash[2][8192];
    __shared__ __align__(16) char Bsh[2][8192];
    int tid = threadIdx.x, lane = tid & 63, wave = tid >> 6;
    int wm = wave >> 1, wn = wave & 1;
    int m0 = byi * 128, n0 = bxi * 128;
    int trow = tid >> 2, kg = tid & 3, tk = kg * 8;
    int l15 = lane & 15, l4 = lane >> 4;
    int wa  = ((trow >> 4) << 10) + (kg << 8) + ((trow & 15) << 4);
    int raA = (wm << 12) + (l4 << 8) + (l15 << 4);
    int raB = (wn << 12) + (l4 << 8) + (l15 << 4);

    f32x4 acc[4][4];
    #pragma unroll
    for (int i = 0; i < 4; ++i)
        #pragma unroll
        for (int j = 0; j < 4; ++j) acc[i][j] = (f32x4){0.f, 0.f, 0.f, 0.f};

    const ushort_t* aP = act  + (size_t)(m0 + trow) * KDN + tk;
    const ushort_t* bP = WdnT + (size_t)(n0 + trow) * KDN + tk;

    auto loadAB = [&](int kt, bf16x8& a0, bf16x8& a1, bf16x8& b0, bf16x8& b1) {
        const ushort_t* p = aP + kt * 32;
        a0 = *(const bf16x8*)p;
        a1 = *(const bf16x8*)(p + 64 * KDN);
        const ushort_t* q = bP + kt * 32;
        b0 = *(const bf16x8*)q;
        b1 = *(const bf16x8*)(q + 64 * KDN);
    };
    auto stage = [&](char* A, char* Bb, bf16x8 a0, bf16x8 a1, bf16x8 b0, bf16x8 b1) {
        *(bf16x8*)(A + wa)         = a0;
        *(bf16x8*)(A + wa + 4096)  = a1;
        *(bf16x8*)(Bb + wa)        = b0;
        *(bf16x8*)(Bb + wa + 4096) = b1;
    };
    auto compute = [&](const char* A, const char* Bb) {
        bf16x8 af[4], bv[4];
        #pragma unroll
        for (int i = 0; i < 4; ++i) {
            af[i] = *(const bf16x8*)(A  + raA + i * 1024);
            bv[i] = *(const bf16x8*)(Bb + raB + i * 1024);
        }
        #pragma unroll
        for (int mi = 0; mi < 4; ++mi)
            #pragma unroll
            for (int ni = 0; ni < 4; ++ni)
                acc[mi][ni] = __builtin_amdgcn_mfma_f32_16x16x32_bf16(af[mi], bv[ni], acc[mi][ni], 0, 0, 0);
    };

    {
        bf16x8 a0, a1, b0, b1;
        loadAB(0, a0, a1, b0, b1);
        stage(Ash[0], Bsh[0], a0, a1, b0, b1);
    }
    __syncthreads();
    for (int kt = 0; kt < 44; kt += 2) {
        bf16x8 a0, a1, b0, b1;
        loadAB(kt + 1, a0, a1, b0, b1);
        compute(Ash[0], Bsh[0]);
        stage(Ash[1], Bsh[1], a0, a1, b0, b1);
        __syncthreads();
        if (kt + 2 < 44) loadAB(kt + 2, a0, a1, b0, b1);
        compute(Ash[1], Bsh[1]);
        if (kt + 2 < 44) {
            stage(Ash[0], Bsh[0], a0, a1, b0, b1);
            __syncthreads();
        }
    }

    #pragma unroll
    for (int ni = 0; ni < 4; ++ni) {
        int col = n0 + wn * 64 + ni * 16 + l15;
        float bd = bdown[col];
        #pragma unroll
        for (int mi = 0; mi < 4; ++mi) {
            int rbase = m0 + wm * 64 + mi * 16 + l4 * 4;
            #pragma unroll
            for (int j = 0; j < 4; ++j) {
                int r = rbase + j;
                y[(size_t)r * DIN + col] = acc[mi][ni][j] + bd + x[(size_t)r * DIN + col];
            }
        }
    }
}

// ---------------------------------------------------------------- launch
extern "C" void kernel_launch(void* const* d_in, const int* in_sizes, int n_in,
                              void* d_out, int out_size, void* d_ws, size_t ws_size,
                              hipStream_t stream) {
    (void)in_sizes; (void)n_in; (void)out_size; (void)ws_size;
    const float* x      = (const float*)d_in[0];
    const float* h_prev = (const float*)d_in[1];
    const float* c_prev = (const float*)d_in[2];
    const float* n_prev = (const float*)d_in[3];
    const float* m_prev = (const float*)d_in[4];
    const float* ln_w   = (const float*)d_in[5];
    const float* ln_b   = (const float*)d_in[6];
    const float* Wz = (const float*)d_in[7];  const float* bz = (const float*)d_in[8];
    const float* Wi = (const float*)d_in[9];  const float* bi = (const float*)d_in[10];
    const float* Wf = (const float*)d_in[11]; const float* bf_ = (const float*)d_in[12];
    const float* Wo = (const float*)d_in[13]; const float* bo = (const float*)d_in[14];
    const float* Rz = (const float*)d_in[15]; const float* rbz = (const float*)d_in[16];
    const float* Ri = (const float*)d_in[17]; const float* rbi = (const float*)d_in[18];
    const float* Rf = (const float*)d_in[19]; const float* rbf = (const float*)d_in[20];
    const float* Ro = (const float*)d_in[21]; const float* rbo = (const float*)d_in[22];
    const float* gn_w = (const float*)d_in[23]; const float* gn_b = (const float*)d_in[24];
    const float* Wup  = (const float*)d_in[25]; const float* bup  = (const float*)d_in[26];
    const float* Wdown = (const float*)d_in[27]; const float* bdown = (const float*)d_in[28];

    // ---- workspace carve (bytes, all 16B-aligned)
    char* w = (char*)d_ws;
    ushort_t* hp_bf  = (ushort_t*)(w);                       // 16,777,216
    ushort_t* WTg    = (ushort_t*)(w + 16777216);            // 10,485,760
    ushort_t* WupT   = (ushort_t*)(w + 27262976);            //  5,767,168
    ushort_t* WdnT   = (ushort_t*)(w + 33030144);            //  2,883,584
    ushort_t* xn_bf  = (ushort_t*)(w + 35913728);            // 16,777,216 (reused as htn)
    ushort_t* htn_bf = xn_bf;
    char*     big    = w + 52690944;
    ushort_t* gates_bf = (ushort_t*)big;                     // 67,108,864 (dead after pointwise)
    ushort_t* up_bf    = (ushort_t*)big;                     // 46,137,344
    ushort_t* act_bf   = (ushort_t*)(big + 46137344);        // 23,068,672
    float* out = (float*)d_out;  // [y, ht, ct, nt, mt]

    prep_hprev <<<4096, 256, 0, stream>>>(h_prev, hp_bf);
    prep_wgates<<<dim3(4, 160, 4), 256, 0, stream>>>(Wz, Wi, Wf, Wo, Rz, Ri, Rf, Ro, WTg);
    prep_wup   <<<dim3(11, 128), 256, 0, stream>>>(Wup, WupT);
    prep_wdown <<<dim3(4, 176), 256, 0, stream>>>(Wdown, WdnT);
    ln_kernel  <<<B_ROWS, 256, 0, stream>>>(x, ln_w, ln_b, xn_bf);

    gemm_gates_bf<<<dim3(8, 64, 4), 256, 0, stream>>>(
        xn_bf, hp_bf, WTg, bz, bi, bf_, bo, rbz, rbi, rbf, rbo, gates_bf);

    pointwise_gn<<<B_ROWS, 256, 0, stream>>>(
        gates_bf, c_prev, n_prev, m_prev, gn_w, gn_b, out, htn_bf);

    gemm_up_bf<<<dim3(22, 64), 256, 0, stream>>>(htn_bf, WupT, bup, up_bf);

    gelu_kernel<<<dim3(6, B_ROWS), 256, 0, stream>>>(up_bf, act_bf);

    gemm_down_bf<<<dim3(8, 64), 256, 0, stream>>>(act_bf, WdnT, bdown, x, out);
}